// Round 11
// baseline (43.187 us; speedup 1.0000x reference)
//
#include <hip/hip_runtime.h>
#include <math.h>

// u: (B=8, T=64, NY=256, NX=256) f32. Residual: (B, 62, NY, NX), center t+1.
// x/y zero-padded, t not padded. Output: sqrt(sum(res^2)).
#define B_    8
#define T_    64
#define NY_   256
#define NX_   256
#define PS_   (NY_ * NX_)

// One wave = YB consecutive y-rows x HALF an x-row (64 lanes x float2 = 128).
// Same 5.0 B/residual as R10 (halo factor 1.25, t-factor 1.26), but 2x waves:
// 4096 = 16/CU, restoring the miss-queue depth R9 had (R10 lost 15% delivery
// rate at 8 waves/CU). Interior x-tile edge comes from a wave-uniform scalar.
#define YB_     8
#define NSTRIP  (NY_ / YB_)                 // 32 strips
#define TCHUNKS 8                           // 7 chunks of 8 t-steps + 1 of 6
#define XH_     2                           // x halves
#define NWAVES  (B_ * NSTRIP * TCHUNKS * XH_)   // 4096 waves = 16/CU
#define NTHREADS 256
#define NBLOCKS  (NWAVES / 4)               // 1024 blocks (8 XCDs x 128)

__device__ __forceinline__ float2 loadf2(const float* p) { return *(const float2*)p; }

// Depth-1 rolling planes (R6-proven). Do NOT register-pipeline an extra plane
// (R4: spills), do NOT fuse finalize (R5: remat), do NOT barrier-couple (R8).
template <int LEN>
__device__ __forceinline__ float strip_accum(const float* __restrict__ u,
                                             int b, int ys, int t0, int xh, int lane) {
    const float a   = 0.04f;                        // 1/DH^2
    const float kdt = 250000.0f / 4840000.0f;       // (1/DT^2)/C^2
    const float k2  = 2.0f * kdt - 4.0f * a;        // coeff of center

    const int y0 = ys * YB_;
    const float m0 = (ys > 0)           ? 1.0f : 0.0f;   // top halo row validity
    const float m5 = (ys < NSTRIP - 1)  ? 1.0f : 0.0f;   // bottom halo row validity
    // Edge substitution: xh=0 -> left edge is domain (0), right edge is real
    // value at x=128; xh=1 -> left edge real at x=127, right edge domain (0).
    const float ehl = (xh != 0) ? 1.0f : 0.0f;
    const float ehr = 1.0f - ehl;
    const int   ex  = xh ? 127 : 128;                    // uniform edge column

    int yoff[YB_ + 2];
    #pragma unroll
    for (int j = 0; j < YB_ + 2; ++j) {
        int y = y0 - 1 + j;
        y = y < 0 ? 0 : (y > NY_ - 1 ? NY_ - 1 : y);
        yoff[j] = y * NX_;
    }

    const float* base = u + ((size_t)b * T_ + t0) * PS_;   // uniform (for edges)
    const float* pl   = base + xh * 128 + lane * 2;        // per-lane vector base

    // Preload: tm (plane t0 centers), c (plane t0+1 rows+halo), cE (edges of t0+1).
    float2 tm[YB_], c[YB_ + 2];
    float  cE[YB_];
    #pragma unroll
    for (int i = 0; i < YB_; ++i) tm[i] = loadf2(pl + yoff[i + 1]);
    const float* p1 = pl + PS_;
    #pragma unroll
    for (int j = 0; j < YB_ + 2; ++j) c[j] = loadf2(p1 + yoff[j]);
    const float* e1 = base + PS_;
    #pragma unroll
    for (int i = 0; i < YB_; ++i) cE[i] = e1[yoff[i + 1] + ex];  // wave-uniform
    c[0].x *= m0; c[0].y *= m0;
    c[YB_+1].x *= m5; c[YB_+1].y *= m5;

    float acc = 0.0f;
    const float* pn = pl + 2 * PS_;
    const float* pe = base + 2 * PS_;
    #pragma unroll
    for (int k = 0; k < LEN; ++k) {
        float2 nn[YB_ + 2];
        float  nE[YB_];
        #pragma unroll
        for (int j = 0; j < YB_ + 2; ++j) nn[j] = loadf2(pn + yoff[j]);
        #pragma unroll
        for (int i = 0; i < YB_; ++i) nE[i] = pe[yoff[i + 1] + ex];
        nn[0].x *= m0; nn[0].y *= m0;
        nn[YB_+1].x *= m5; nn[YB_+1].y *= m5;

        #pragma unroll
        for (int i = 0; i < YB_; ++i) {
            float2 ctr = c[i + 1], up = c[i], dn = c[i + 2];
            float2 t = tm[i], nf = nn[i + 1];
            float clv = __shfl_up(ctr.y, 1, 64);
            float crv = __shfl_down(ctr.x, 1, 64);
            float cl = (lane == 0)  ? ehl * cE[i] : clv;
            float cr = (lane == 63) ? ehr * cE[i] : crv;

            {
                float s2 = cl + ctr.y + up.x + dn.x;
                float r = fmaf(s2, a, fmaf(t.x + nf.x, -kdt, ctr.x * k2));
                acc = fmaf(r, r, acc);
            }
            {
                float s2 = ctr.x + cr + up.y + dn.y;
                float r = fmaf(s2, a, fmaf(t.y + nf.y, -kdt, ctr.y * k2));
                acc = fmaf(r, r, acc);
            }
        }

        #pragma unroll
        for (int i = 0; i < YB_; ++i) tm[i] = c[i + 1];
        #pragma unroll
        for (int j = 0; j < YB_ + 2; ++j) c[j] = nn[j];
        #pragma unroll
        for (int i = 0; i < YB_; ++i) cE[i] = nE[i];
        pn += PS_;
        pe += PS_;
    }
    return acc;
}

__global__ __launch_bounds__(NTHREADS, 4)
void pinn_residual_partial(const float* __restrict__ u, float* __restrict__ partial) {
    const int lane = threadIdx.x & 63;
    const int w    = threadIdx.x >> 6;

    // XCD-aware mapping (proven: FETCH 123->82 MB): b = bid&7 pins each batch
    // (16.8 MB) to one XCD's L2. 1024 blocks = 8 x 128, bijective.
    const int b     = blockIdx.x & 7;
    const int inner = blockIdx.x >> 3;             // 0..127
    const int ysg   = inner & 7;                   // strip-group fastest (halo locality)
    const int xh    = (inner >> 3) & 1;
    const int tc    = inner >> 4;                  // 0..7
    const int ys    = ysg * 4 + w;                 // 4 consecutive strips per block
    const int t0    = tc * 8;

    float s;
    if (tc < TCHUNKS - 1) s = strip_accum<8>(u, b, ys, t0, xh, lane);
    else                  s = strip_accum<6>(u, b, ys, t0, xh, lane);

    #pragma unroll
    for (int off = 32; off > 0; off >>= 1)
        s += __shfl_down(s, off, 64);

    __shared__ float lds[NTHREADS / 64];
    if (lane == 0) lds[w] = s;
    __syncthreads();
    if (threadIdx.x == 0) {
        float bs = lds[0] + lds[1] + lds[2] + lds[3];
        partial[blockIdx.x] = bs;   // every slot written every launch
    }
}

__global__ __launch_bounds__(NTHREADS)
void pinn_finalize(const float* __restrict__ partial, float* __restrict__ out) {
    float s = 0.0f;
    for (int i = threadIdx.x; i < NBLOCKS; i += NTHREADS)
        s += partial[i];
    #pragma unroll
    for (int off = 32; off > 0; off >>= 1)
        s += __shfl_down(s, off, 64);
    __shared__ float lds[NTHREADS / 64];
    int lane = threadIdx.x & 63;
    int wid  = threadIdx.x >> 6;
    if (lane == 0) lds[wid] = s;
    __syncthreads();
    if (threadIdx.x == 0) {
        float bs = 0.0f;
        #pragma unroll
        for (int q = 0; q < NTHREADS / 64; ++q) bs += lds[q];
        out[0] = sqrtf(bs);
    }
}

extern "C" void kernel_launch(void* const* d_in, const int* in_sizes, int n_in,
                              void* d_out, int out_size, void* d_ws, size_t ws_size,
                              hipStream_t stream) {
    const float* u = (const float*)d_in[0];
    float* partial = (float*)d_ws;              // NBLOCKS floats = 4 KiB scratch
    float* out     = (float*)d_out;

    pinn_residual_partial<<<NBLOCKS, NTHREADS, 0, stream>>>(u, partial);
    pinn_finalize<<<1, NTHREADS, 0, stream>>>(partial, out);
}

// Round 12
// 31.512 us; speedup vs baseline: 1.3705x; 1.3705x over previous
//
#include <hip/hip_runtime.h>
#include <math.h>

// u: (B=8, T=64, NY=256, NX=256) f32. Residual: (B, 62, NY, NX), center t+1.
// x/y zero-padded, t not padded. Output: sqrt(sum(res^2)).
//
// FINAL STRUCTURE (R9, best of 11 rounds at 31.1 us):
//  - wave = 4 y-rows x full x-row (64 lanes x float4), t-rolled in registers
//  - 2 planes per loop iter: 12 batched loads -> latency paid once per 2 steps
//  - XCD-pinned mapping (b = bid&7): FETCH 123->82 MB
//  - separate finalize kernel
// Probed and REJECTED (each attributed):
//  R4  register pipeline     -> allocator flip, 200MB spills
//  R5  fused finalize        -> 52-VGPR remat, 2x
//  R7  YB=2 occupancy x2     -> +30% traffic, net -10%
//  R8  LDS stage + barrier   -> lockstep kills independent-wave hiding
//  R10 YB=8 traffic -15%     -> miss-queue underfill at 8 waves/CU, neutral
//  R11 x-split float2        -> 64-VGPR allocator cliff, -40%
#define B_    8
#define T_    64
#define NY_   256
#define NX_   256
#define PS_   (NY_ * NX_)

#define YB_     4
#define NSTRIP  (NY_ / YB_)                 // 64 strips
#define TCHUNKS 8                           // 7 chunks of 8 t-steps + 1 of 6
#define NWAVES  (B_ * NSTRIP * TCHUNKS)     // 4096 waves = 16/CU
#define NTHREADS 256
#define NBLOCKS  (NWAVES / 4)               // 1024 blocks (8 XCDs x 128)

__device__ __forceinline__ float4 loadf4(const float* p) { return *(const float4*)p; }

__device__ __forceinline__ void step_t(float4 (&tm)[YB_], float4 (&c)[YB_ + 2],
                                       const float4 (&nf)[YB_ + 2], float& acc,
                                       float xl, float xr) {
    const float a   = 0.04f;                        // 1/DH^2
    const float kdt = 250000.0f / 4840000.0f;       // (1/DT^2)/C^2
    const float k2  = 2.0f * kdt - 4.0f * a;        // coeff of center

    #pragma unroll
    for (int i = 0; i < YB_; ++i) {
        float4 ctr = c[i + 1], up = c[i], dn = c[i + 2];
        float4 t = tm[i], n = nf[i + 1];
        float cl = __shfl_up(ctr.w, 1, 64) * xl;
        float cr = __shfl_down(ctr.x, 1, 64) * xr;

        {
            float s2 = cl + ctr.y + up.x + dn.x;
            float r = fmaf(s2, a, fmaf(t.x + n.x, -kdt, ctr.x * k2));
            acc = fmaf(r, r, acc);
        }
        {
            float s2 = ctr.x + ctr.z + up.y + dn.y;
            float r = fmaf(s2, a, fmaf(t.y + n.y, -kdt, ctr.y * k2));
            acc = fmaf(r, r, acc);
        }
        {
            float s2 = ctr.y + ctr.w + up.z + dn.z;
            float r = fmaf(s2, a, fmaf(t.z + n.z, -kdt, ctr.z * k2));
            acc = fmaf(r, r, acc);
        }
        {
            float s2 = ctr.z + cr + up.w + dn.w;
            float r = fmaf(s2, a, fmaf(t.w + n.w, -kdt, ctr.w * k2));
            acc = fmaf(r, r, acc);
        }
    }
    #pragma unroll
    for (int i = 0; i < YB_; ++i) tm[i] = c[i + 1];
    #pragma unroll
    for (int j = 0; j < YB_ + 2; ++j) c[j] = nf[j];
}

template <int LEN>   // LEN must be even
__device__ __forceinline__ float strip_accum(const float* __restrict__ u,
                                             int b, int ys, int t0, int lane) {
    static_assert(LEN % 2 == 0, "LEN even");
    const int y0 = ys * YB_;
    const float m0 = (ys > 0)           ? 1.0f : 0.0f;
    const float m5 = (ys < NSTRIP - 1)  ? 1.0f : 0.0f;
    const float xl = (lane > 0)  ? 1.0f : 0.0f;
    const float xr = (lane < 63) ? 1.0f : 0.0f;

    int yoff[YB_ + 2];
    #pragma unroll
    for (int j = 0; j < YB_ + 2; ++j) {
        int y = y0 - 1 + j;
        y = y < 0 ? 0 : (y > NY_ - 1 ? NY_ - 1 : y);
        yoff[j] = y * NX_;
    }

    const float* pl = u + ((size_t)b * T_ + t0) * PS_ + lane * 4;

    float4 tm[YB_], c[YB_ + 2];
    #pragma unroll
    for (int i = 0; i < YB_; ++i) tm[i] = loadf4(pl + yoff[i + 1]);
    const float* p1 = pl + PS_;
    #pragma unroll
    for (int j = 0; j < YB_ + 2; ++j) c[j] = loadf4(p1 + yoff[j]);
    c[0].x *= m0; c[0].y *= m0; c[0].z *= m0; c[0].w *= m0;
    c[YB_+1].x *= m5; c[YB_+1].y *= m5; c[YB_+1].z *= m5; c[YB_+1].w *= m5;

    float acc = 0.0f;
    const float* pn = pl + 2 * PS_;
    #pragma unroll
    for (int k = 0; k < LEN; k += 2) {
        float4 nA[YB_ + 2], nB[YB_ + 2];
        #pragma unroll
        for (int j = 0; j < YB_ + 2; ++j) nA[j] = loadf4(pn + yoff[j]);
        #pragma unroll
        for (int j = 0; j < YB_ + 2; ++j) nB[j] = loadf4(pn + PS_ + yoff[j]);
        nA[0].x *= m0; nA[0].y *= m0; nA[0].z *= m0; nA[0].w *= m0;
        nA[YB_+1].x *= m5; nA[YB_+1].y *= m5; nA[YB_+1].z *= m5; nA[YB_+1].w *= m5;
        nB[0].x *= m0; nB[0].y *= m0; nB[0].z *= m0; nB[0].w *= m0;
        nB[YB_+1].x *= m5; nB[YB_+1].y *= m5; nB[YB_+1].z *= m5; nB[YB_+1].w *= m5;

        step_t(tm, c, nA, acc, xl, xr);
        step_t(tm, c, nB, acc, xl, xr);
        pn += 2 * PS_;
    }
    return acc;
}

__global__ __launch_bounds__(NTHREADS, 4)
void pinn_residual_partial(const float* __restrict__ u, float* __restrict__ partial) {
    const int lane = threadIdx.x & 63;
    const int w    = threadIdx.x >> 6;

    const int b     = blockIdx.x & 7;
    const int inner = blockIdx.x >> 3;             // 0..127
    const int wl    = inner * 4 + w;               // 0..511 within batch
    const int ys = wl & (NSTRIP - 1);
    const int tc = wl >> 6;                        // 0..7
    const int t0 = tc * 8;

    float s;
    if (tc < TCHUNKS - 1) s = strip_accum<8>(u, b, ys, t0, lane);
    else                  s = strip_accum<6>(u, b, ys, t0, lane);

    #pragma unroll
    for (int off = 32; off > 0; off >>= 1)
        s += __shfl_down(s, off, 64);

    __shared__ float lds[NTHREADS / 64];
    if (lane == 0) lds[w] = s;
    __syncthreads();
    if (threadIdx.x == 0) {
        float bs = lds[0] + lds[1] + lds[2] + lds[3];
        partial[blockIdx.x] = bs;   // every slot written every launch
    }
}

__global__ __launch_bounds__(NTHREADS)
void pinn_finalize(const float* __restrict__ partial, float* __restrict__ out) {
    float s = 0.0f;
    for (int i = threadIdx.x; i < NBLOCKS; i += NTHREADS)
        s += partial[i];
    #pragma unroll
    for (int off = 32; off > 0; off >>= 1)
        s += __shfl_down(s, off, 64);
    __shared__ float lds[NTHREADS / 64];
    int lane = threadIdx.x & 63;
    int wid  = threadIdx.x >> 6;
    if (lane == 0) lds[wid] = s;
    __syncthreads();
    if (threadIdx.x == 0) {
        float bs = 0.0f;
        #pragma unroll
        for (int q = 0; q < NTHREADS / 64; ++q) bs += lds[q];
        out[0] = sqrtf(bs);
    }
}

extern "C" void kernel_launch(void* const* d_in, const int* in_sizes, int n_in,
                              void* d_out, int out_size, void* d_ws, size_t ws_size,
                              hipStream_t stream) {
    const float* u = (const float*)d_in[0];
    float* partial = (float*)d_ws;              // NBLOCKS floats = 4 KiB scratch
    float* out     = (float*)d_out;

    pinn_residual_partial<<<NBLOCKS, NTHREADS, 0, stream>>>(u, partial);
    pinn_finalize<<<1, NTHREADS, 0, stream>>>(partial, out);
}